// Round 1
// baseline (350.452 us; speedup 1.0000x reference)
//
#include <hip/hip_runtime.h>

// LSTM B=2048, T=1024, H=50. Round 14: shorten the per-step recurrence chain.
//  - Parallel split-K MFMAs (two independent accumulator pairs + VALU add)
//    instead of the 2-deep chained MFMA: saves one MFMA latency per step.
//  - x/bias contribution moved from B-operand slots (k=56..60) into the MFMA
//    C-operand init: zc[r] = fma(zw[r], x_t, zb[r]) per lane (exact f32, only
//    the lane's own unit j matters since other rows' outputs are discarded).
//    B1 is now a plain ds_read_b128; all cndmask B-construction deleted.
//    x_t prefetched one step ahead from XT (recurrence-independent).
//  - Cell state tracked pre-scaled (c2 = 2*log2e*c): drops one mul from the
//    c -> exp2 -> h critical chain (Q2 = 2λ(1+Ef) computed off-chain).
//
// grid=256 (1 block/CU), block=448 = 7 waves. Wave w owns gate-row tiles
// 2w, 2w+1 (permuted rows n'=4j+g). Lane (kq,L15): unit j = 8w+4*(L15>>3)+kq,
// batch bl = L15&7 (L15/L15+8 same hb row -> free broadcast).
// A = scaled W_hh' single f16 in VGPRs (i,f,o rows x -log2e; g rows x +2log2e
// -> exp2-only epilogue). A K-slots 0-49 = W_hh, 50-63 zero.
// One barrier per step; halves unrolled x2 for static double-buffer addrs.

#define H     50
#define TT    1024
#define BATCH 2048
#define BW    8
#define NTHR  448     // 7 waves
#define KP    80      // f16 per hb row (40-word stride, measured conflict-free)

typedef float    f32x4 __attribute__((ext_vector_type(4)));
typedef _Float16 f16x8 __attribute__((ext_vector_type(8)));

__global__ __launch_bounds__(NTHR, 1) void lstm_kernel(
    const float* __restrict__ x,      // [B, T]
    const float* __restrict__ W_ih,   // [200]
    const float* __restrict__ W_hh,   // [200, 50]
    const float* __restrict__ b_ih,   // [200]
    const float* __restrict__ b_hh,   // [200]
    const float* __restrict__ W_lin,  // [50]
    const float* __restrict__ b_lin,  // [1]
    float* __restrict__ out)          // [B]
{
    __shared__ _Float16 hb[2][BW][KP];    // h^T, double-buffered
    __shared__ float    XT[TT + 2][BW];   // x per (t, b), f32, +2 pad rows
    __shared__ float    redH[H][BW];      // head reduction

    const int tid  = threadIdx.x;
    const int wave = tid >> 6;
    const int lane = tid & 63;
    const int L15  = lane & 15;
    const int kq   = lane >> 4;
    const int bl   = L15 & 7;
    const int b0   = blockIdx.x * BW;
    const int t0   = 2 * wave;            // tiles t0, t0+1

    const float LOG2E  = 1.4426950408889634f;
    const float LOG2E2 = 2.8853900817779268f;

    // ---- A fragments: scaled permuted W_hh rows (k 0..49 only), f16 ----
    f16x8 A[2][2];
    #pragma unroll
    for (int tt = 0; tt < 2; ++tt) {
        const int m  = (t0 + tt) * 16 + L15;    // gate-row n' = 4j+g
        const int jm = m >> 2, gm = m & 3;
        const bool v = (jm < H);
        const float s = (gm == 2) ? LOG2E2 : -LOG2E;
        #pragma unroll
        for (int kf = 0; kf < 2; ++kf) {
            f16x8 vv;
            #pragma unroll
            for (int e = 0; e < 8; ++e) {
                const int k = kf * 32 + kq * 8 + e;
                _Float16 val = (_Float16)0.f;
                if (v && k < H) val = (_Float16)(s * W_hh[(gm * H + jm) * H + k]);
                vv[e] = val;
            }
            A[tt][kf] = vv;
        }
    }

    // ---- this lane's unit + exact f32 x-path coefficients (C-init) ----
    const int  j  = 8 * wave + ((L15 >> 3) << 2) + kq;   // 0..55 (50-55 pad)
    const bool jv = (j < H);
    const float wlin = jv ? W_lin[j] : 0.f;
    float zw[4], zb[4];                                  // scaled W_ih, bias
    #pragma unroll
    for (int r = 0; r < 4; ++r) {
        const float s = (r == 2) ? LOG2E2 : -LOG2E;
        zw[r] = jv ? s * W_ih[r * H + j] : 0.f;
        zb[r] = jv ? s * (b_ih[r * H + j] + b_hh[r * H + j]) : 0.f;
    }

    // ---- init: zero hb; fill XT from global x (coalesced in t) ----
    for (int i = tid; i < 2 * BW * KP; i += NTHR)
        ((_Float16*)hb)[i] = (_Float16)0.f;
    for (int i = tid; i < TT * BW; i += NTHR) {
        const int bb = i >> 10, t = i & 1023;
        XT[t][bb] = x[(size_t)(b0 + bb) * TT + t];
    }
    if (tid < 2 * BW) ((float*)&XT[TT][0])[tid] = 0.f;   // pad rows for prefetch

    float c2 = 0.f;        // scaled cell state: 2*log2e * c
    float hlast = 0.f;
    __syncthreads();

    float xt_cur = XT[0][bl];          // x for step 0
    const bool lo = (L15 < 8);

    #pragma unroll 1
    for (int tbase = 0; tbase < TT; tbase += 2) {
        #pragma unroll
        for (int half = 0; half < 2; ++half) {
            const int t = tbase + half;
            const _Float16* hp = &hb[half][bl][0];        // cur buffer
            _Float16*       np = &hb[half ^ 1][bl][0];    // next buffer

            // ---- B fragments: plain reads, k 0..31 and 32..63 ----
            const f16x8 B0 = *(const f16x8*)(hp + kq * 8);
            const f16x8 B1 = *(const f16x8*)(hp + 32 + kq * 8);

            // ---- C-init: gx for this lane's unit (exact f32) ----
            f32x4 zc;
            #pragma unroll
            for (int r = 0; r < 4; ++r)
                zc[r] = __builtin_fmaf(zw[r], xt_cur, zb[r]);
            const f32x4 zz = {0.f, 0.f, 0.f, 0.f};

            // ---- 4 MFMAs: two PARALLEL split-K pairs (1 MFMA latency) ----
            f32x4 a0 = __builtin_amdgcn_mfma_f32_16x16x32_f16(A[0][0], B0, zc, 0, 0, 0);
            f32x4 a1 = __builtin_amdgcn_mfma_f32_16x16x32_f16(A[1][0], B0, zc, 0, 0, 0);
            f32x4 p0 = __builtin_amdgcn_mfma_f32_16x16x32_f16(A[0][1], B1, zz, 0, 0, 0);
            f32x4 p1 = __builtin_amdgcn_mfma_f32_16x16x32_f16(A[1][1], B1, zz, 0, 0, 0);

            // prefetch x for next step (XT padded; latency hides under epilogue)
            xt_cur = XT[t + 1][bl];

            // ---- combine + select this lane's tile ----
            const float gi = lo ? (a0[0] + p0[0]) : (a1[0] + p1[0]);
            const float gf = lo ? (a0[1] + p0[1]) : (a1[1] + p1[1]);
            const float gg = lo ? (a0[2] + p0[2]) : (a1[2] + p1[2]);
            const float go = lo ? (a0[3] + p0[3]) : (a1[3] + p1[3]);

            // ---- fused epilogue (exp2-only), scaled-c2 form ----
            const float Ei = __builtin_amdgcn_exp2f(gi);
            const float Ef = __builtin_amdgcn_exp2f(gf);
            const float Eg = __builtin_amdgcn_exp2f(gg);
            const float Eo = __builtin_amdgcn_exp2f(go);
            const float P  = (1.0f + Ei) * (1.0f + Eg);
            const float Q  = 1.0f + Ef;
            const float Q2 = __builtin_fmaf(LOG2E2, Ef, LOG2E2);    // 2λ(1+Ef)
            const float num = __builtin_fmaf(c2, P, (Eg - 1.0f) * Q2);
            c2 = num * __builtin_amdgcn_rcpf(P * Q);
            const float ca = fminf(c2, 80.0f);
            const float Ec = __builtin_amdgcn_exp2f(ca);
            const float h  = (Ec - 1.0f) *
                __builtin_amdgcn_rcpf((1.0f + Eo) * (1.0f + Ec));
            hlast = h;

            np[j] = (_Float16)h;   // unguarded: pad j -> zero-A slots 50-55
            __syncthreads();
        }
    }

    // ---- head: out[b] = b_lin + sum_j W_lin[j] * h[j][b] ----
    if (jv) redH[j][bl] = wlin * hlast;
    __syncthreads();
    if (tid < BW) {
        float s = b_lin[0];
        #pragma unroll 10
        for (int jj = 0; jj < H; ++jj) s += redH[jj][tid];
        out[b0 + tid] = s;
    }
}

extern "C" void kernel_launch(void* const* d_in, const int* in_sizes, int n_in,
                              void* d_out, int out_size, void* d_ws, size_t ws_size,
                              hipStream_t stream) {
    const float* x     = (const float*)d_in[0];
    const float* W_ih  = (const float*)d_in[1];
    const float* W_hh  = (const float*)d_in[2];
    const float* b_ih  = (const float*)d_in[3];
    const float* b_hh  = (const float*)d_in[4];
    const float* W_lin = (const float*)d_in[5];
    const float* b_lin = (const float*)d_in[6];
    float* out = (float*)d_out;

    dim3 grid(BATCH / BW);    // 256 blocks, 1 per CU
    dim3 block(NTHR);         // 7 waves
    lstm_kernel<<<grid, block, 0, stream>>>(x, W_ih, W_hh, b_ih, b_hh,
                                            W_lin, b_lin, out);
}

// Round 2
// 338.714 us; speedup vs baseline: 1.0347x; 1.0347x over previous
//
#include <hip/hip_runtime.h>

// LSTM B=2048, T=1024, H=50. Round 15: 2 workgroups per CU to fill the
// recurrence-latency bubbles.
//  - grid=512, BW=4 batches/block, block=256 = 4 waves. Two blocks co-resident
//    per CU with INDEPENDENT barriers -> phase slip hides ds_read latency,
//    trans-chain latency and barrier cost of each other.
//  - Each wave owns 4 gate-row tiles (tiles 4w..4w+3 of 13; permuted rows
//    n'=4j+g). B columns = 4 batches x 4 replicas. Lane (kq,L15):
//    batch bl=L15&3, tile-select ts=L15>>2, unit j=16w+4ts+kq (pad j>=50).
//  - 8 MFMAs/wave/step: 4 independent 2-deep split-K chains (R14 showed
//    parallel+VALU-add is a net loss; chains hide each other's latency).
//  - Keeps R14 wins: gx folded into MFMA C-init (exact f32, B1 is a plain
//    ds_read_b128), cell state pre-scaled (c2 = 2*log2e*c), exp2-only
//    epilogue via scaled-f16 A (i,f,o rows x -log2e; g rows x +2log2e).
// One barrier per step; halves unrolled x2 for static double-buffer addrs.

#define H     50
#define TT    1024
#define BATCH 2048
#define BW    4
#define NTHR  256     // 4 waves
#define NTILE 4       // gate-row tiles per wave
#define KP    80      // f16 per hb row (40-word stride)

typedef float    f32x4 __attribute__((ext_vector_type(4)));
typedef _Float16 f16x8 __attribute__((ext_vector_type(8)));

__global__ __launch_bounds__(NTHR, 2) void lstm_kernel(
    const float* __restrict__ x,      // [B, T]
    const float* __restrict__ W_ih,   // [200]
    const float* __restrict__ W_hh,   // [200, 50]
    const float* __restrict__ b_ih,   // [200]
    const float* __restrict__ b_hh,   // [200]
    const float* __restrict__ W_lin,  // [50]
    const float* __restrict__ b_lin,  // [1]
    float* __restrict__ out)          // [B]
{
    __shared__ _Float16 hb[2][BW][KP];    // h^T, double-buffered
    __shared__ float    XT[TT + 2][BW];   // x per (t, b), f32, +2 pad rows
    __shared__ float    redH[H][BW];      // head reduction

    const int tid  = threadIdx.x;
    const int wave = tid >> 6;
    const int lane = tid & 63;
    const int L15  = lane & 15;
    const int kq   = lane >> 4;
    const int bl   = L15 & 3;
    const int b0   = blockIdx.x * BW;

    const float LOG2E  = 1.4426950408889634f;
    const float LOG2E2 = 2.8853900817779268f;

    // ---- A fragments: scaled permuted W_hh rows (k 0..49 only), f16 ----
    f16x8 A[NTILE][2];
    #pragma unroll
    for (int tt = 0; tt < NTILE; ++tt) {
        const int m  = (NTILE * wave + tt) * 16 + L15;   // gate-row n' = 4j+g
        const int jm = m >> 2, gm = m & 3;
        const bool v = (jm < H);
        const float s = (gm == 2) ? LOG2E2 : -LOG2E;
        #pragma unroll
        for (int kf = 0; kf < 2; ++kf) {
            f16x8 vv;
            #pragma unroll
            for (int e = 0; e < 8; ++e) {
                const int k = kf * 32 + kq * 8 + e;
                _Float16 val = (_Float16)0.f;
                if (v && k < H) val = (_Float16)(s * W_hh[(gm * H + jm) * H + k]);
                vv[e] = val;
            }
            A[tt][kf] = vv;
        }
    }

    // ---- this lane's unit + exact f32 x-path coefficients (C-init) ----
    const int  j  = 16 * wave + 4 * (L15 >> 2) + kq;     // 0..63 (50-63 pad)
    const bool jv = (j < H);
    const float wlin = jv ? W_lin[j] : 0.f;
    float zw[4], zb[4];                                  // scaled W_ih, bias
    #pragma unroll
    for (int r = 0; r < 4; ++r) {
        const float s = (r == 2) ? LOG2E2 : -LOG2E;
        zw[r] = jv ? s * W_ih[r * H + j] : 0.f;
        zb[r] = jv ? s * (b_ih[r * H + j] + b_hh[r * H + j]) : 0.f;
    }

    // ---- init: zero hb; fill XT from global x (coalesced in t) ----
    for (int i = tid; i < 2 * BW * KP; i += NTHR)
        ((_Float16*)hb)[i] = (_Float16)0.f;
    for (int i = tid; i < TT * BW; i += NTHR) {
        const int bb = i >> 10, t = i & 1023;
        XT[t][bb] = x[(size_t)(b0 + bb) * TT + t];
    }
    if (tid < 2 * BW) ((float*)&XT[TT][0])[tid] = 0.f;   // pad rows for prefetch

    float c2 = 0.f;        // scaled cell state: 2*log2e * c
    float hlast = 0.f;
    __syncthreads();

    float xt_cur = XT[0][bl];          // x for step 0
    const bool s0 = (L15 & 4) != 0;    // tile-select bit 0
    const bool s1 = (L15 & 8) != 0;    // tile-select bit 1

    #pragma unroll 1
    for (int tbase = 0; tbase < TT; tbase += 2) {
        #pragma unroll
        for (int half = 0; half < 2; ++half) {
            const int t = tbase + half;
            const _Float16* hp = &hb[half][bl][0];        // cur buffer
            _Float16*       np = &hb[half ^ 1][bl][0];    // next buffer

            // ---- B fragments: plain reads, k 0..31 and 32..63 ----
            const f16x8 B0 = *(const f16x8*)(hp + kq * 8);
            const f16x8 B1 = *(const f16x8*)(hp + 32 + kq * 8);

            // ---- C-init: gx for this lane's unit (exact f32) ----
            f32x4 zc;
            #pragma unroll
            for (int r = 0; r < 4; ++r)
                zc[r] = __builtin_fmaf(zw[r], xt_cur, zb[r]);

            // ---- 8 MFMAs: 4 independent 2-deep split-K chains ----
            f32x4 a0 = __builtin_amdgcn_mfma_f32_16x16x32_f16(A[0][0], B0, zc, 0, 0, 0);
            f32x4 a1 = __builtin_amdgcn_mfma_f32_16x16x32_f16(A[1][0], B0, zc, 0, 0, 0);
            f32x4 a2 = __builtin_amdgcn_mfma_f32_16x16x32_f16(A[2][0], B0, zc, 0, 0, 0);
            f32x4 a3 = __builtin_amdgcn_mfma_f32_16x16x32_f16(A[3][0], B0, zc, 0, 0, 0);
            a0 = __builtin_amdgcn_mfma_f32_16x16x32_f16(A[0][1], B1, a0, 0, 0, 0);
            a1 = __builtin_amdgcn_mfma_f32_16x16x32_f16(A[1][1], B1, a1, 0, 0, 0);
            a2 = __builtin_amdgcn_mfma_f32_16x16x32_f16(A[2][1], B1, a2, 0, 0, 0);
            a3 = __builtin_amdgcn_mfma_f32_16x16x32_f16(A[3][1], B1, a3, 0, 0, 0);

            // prefetch x for next step (XT padded; hides under epilogue)
            xt_cur = XT[t + 1][bl];

            // ---- select this lane's tile: 3-cndmask tree per gate ----
            float g[4];
            #pragma unroll
            for (int r = 0; r < 4; ++r) {
                const float m01 = s0 ? a1[r] : a0[r];
                const float m23 = s0 ? a3[r] : a2[r];
                g[r] = s1 ? m23 : m01;
            }

            // ---- fused epilogue (exp2-only), scaled-c2 form ----
            const float Ei = __builtin_amdgcn_exp2f(g[0]);
            const float Ef = __builtin_amdgcn_exp2f(g[1]);
            const float Eg = __builtin_amdgcn_exp2f(g[2]);
            const float Eo = __builtin_amdgcn_exp2f(g[3]);
            const float P  = (1.0f + Ei) * (1.0f + Eg);
            const float Q  = 1.0f + Ef;
            const float Q2 = __builtin_fmaf(LOG2E2, Ef, LOG2E2);    // 2λ(1+Ef)
            const float num = __builtin_fmaf(c2, P, (Eg - 1.0f) * Q2);
            c2 = num * __builtin_amdgcn_rcpf(P * Q);
            const float ca = fminf(c2, 80.0f);
            const float Ec = __builtin_amdgcn_exp2f(ca);
            const float h  = (Ec - 1.0f) *
                __builtin_amdgcn_rcpf((1.0f + Eo) * (1.0f + Ec));
            hlast = h;

            np[j] = (_Float16)h;   // unguarded: pad j -> zero-A slots 50-63
            __syncthreads();
        }
    }

    // ---- head: out[b] = b_lin + sum_j W_lin[j] * h[j][b] ----
    if (jv) redH[j][bl] = wlin * hlast;
    __syncthreads();
    if (tid < BW) {
        float s = b_lin[0];
        #pragma unroll 10
        for (int jj = 0; jj < H; ++jj) s += redH[jj][tid];
        out[b0 + tid] = s;
    }
}

extern "C" void kernel_launch(void* const* d_in, const int* in_sizes, int n_in,
                              void* d_out, int out_size, void* d_ws, size_t ws_size,
                              hipStream_t stream) {
    const float* x     = (const float*)d_in[0];
    const float* W_ih  = (const float*)d_in[1];
    const float* W_hh  = (const float*)d_in[2];
    const float* b_ih  = (const float*)d_in[3];
    const float* b_hh  = (const float*)d_in[4];
    const float* W_lin = (const float*)d_in[5];
    const float* b_lin = (const float*)d_in[6];
    float* out = (float*)d_out;

    dim3 grid(BATCH / BW);    // 512 blocks, 2 per CU
    dim3 block(NTHR);         // 4 waves
    lstm_kernel<<<grid, block, 0, stream>>>(x, W_ih, W_hh, b_ih, b_hh,
                                            W_lin, b_lin, out);
}